// Round 4
// baseline (439.557 us; speedup 1.0000x reference)
//
#include <hip/hip_runtime.h>

#define NN 50000
#define NE 800000
#define DIM 128
#define NEG_SLOPE 0.1f

// ---------- preprocessing: CSR-by-dst build ----------

__global__ void k_init(float* __restrict__ deg, int* __restrict__ hist) {
    int i = blockIdx.x * 256 + threadIdx.x;
    if (i < NN) { deg[i] = 1.0f; hist[i] = 0; }   // self-loop weight 1
}

__global__ void k_deg_hist(const int* __restrict__ ei, const float* __restrict__ attr,
                           const int* __restrict__ etype, const float* __restrict__ scale,
                           float* __restrict__ deg, int* __restrict__ hist) {
    int e = blockIdx.x * 256 + threadIdx.x;
    if (e >= NE) return;
    float w = scale[etype[e]] * attr[e];
    int d = ei[NE + e];
    atomicAdd(&deg[d], w);
    atomicAdd(&hist[d], 1);
}

// scan1: per-block (1024 elems) exclusive scan -> rowptr, block sums -> aux.
// Also converts deg -> dinv in place.
__global__ void k_scan1(const int* __restrict__ hist, int* __restrict__ rowptr,
                        int* __restrict__ aux, float* __restrict__ deg) {
    __shared__ int sdata[256];
    int t = threadIdx.x;
    int base = blockIdx.x * 1024 + t * 4;
    int v[4]; int s = 0;
    #pragma unroll
    for (int j = 0; j < 4; ++j) { v[j] = (base + j < NN) ? hist[base + j] : 0; s += v[j]; }
    #pragma unroll
    for (int j = 0; j < 4; ++j) {
        if (base + j < NN) {
            float d = deg[base + j];
            deg[base + j] = d > 0.0f ? (1.0f / sqrtf(d)) : 0.0f;
        }
    }
    sdata[t] = s;
    __syncthreads();
    for (int off = 1; off < 256; off <<= 1) {
        int x = (t >= off) ? sdata[t - off] : 0;
        __syncthreads();
        sdata[t] += x;
        __syncthreads();
    }
    int run = sdata[t] - s;
    if (t == 255) aux[blockIdx.x] = sdata[255];
    #pragma unroll
    for (int j = 0; j < 4; ++j) { if (base + j < NN) rowptr[base + j] = run; run += v[j]; }
}

__global__ void k_scan2(int* __restrict__ aux) {
    int t = threadIdx.x;
    int v = (t < 49) ? aux[t] : 0;
    int orig = v;
    for (int off = 1; off < 64; off <<= 1) {
        int y = __shfl_up(v, off, 64);
        if (t >= off) v += y;
    }
    if (t < 49) aux[t] = v - orig;
}

__global__ void k_scan3(int* __restrict__ rowptr, int* __restrict__ hist,
                        const int* __restrict__ aux) {
    int i = blockIdx.x * 256 + threadIdx.x;
    if (i < NN) {
        int v = rowptr[i] + aux[i >> 10];
        rowptr[i] = v;
        hist[i] = v;
    }
    if (i == 0) rowptr[NN] = NE;
}

// place edges into CSR order; store packed {src, dinv[src]*w} (dinv[dst] folded
// into a final per-row scale inside k_layer).
__global__ void k_place(const int* __restrict__ ei, const float* __restrict__ attr,
                        const int* __restrict__ etype, const float* __restrict__ scale,
                        const float* __restrict__ dinv, int* __restrict__ cursor,
                        int2* __restrict__ epack) {
    int e = blockIdx.x * 256 + threadIdx.x;
    if (e >= NE) return;
    int s = ei[e], d = ei[NE + e];
    float w = scale[etype[e]] * attr[e];
    int pos = atomicAdd(&cursor[d], 1);
    int2 pk; pk.x = s; pk.y = __float_as_int(dinv[s] * w);
    epack[pos] = pk;
}

// ---------- fused layer: out = leaky?( (agg(xin) + dinv^2 xin) @ W + b ) ----------
// Block = 256 threads = 4 waves; 16 dst rows per block (NN = 3125*16, exact grid).
// Gather: each wave runs 2 independent 32-lane streams (lanes 0-31 / 32-63);
// a stream covers a full row with float4 per lane and walks its edge list with a
// depth-8 load pipeline (8x 1KB wave-loads in flight). Edge meta is packed int2.
// GEMM: 16x128 @ 128x128 register-blocked from LDS (acc[2][4]/thread).
template<bool LEAKY>
__global__ __launch_bounds__(256, 4)
void k_layer(const float* __restrict__ xin, const int2* __restrict__ epack,
             const int* __restrict__ rowptr, const float* __restrict__ dinv,
             const float* __restrict__ W, const float* __restrict__ b,
             float* __restrict__ out) {
    __shared__ float Xs[16][132];
    int tid = threadIdx.x;
    int row0 = blockIdx.x * 16;
    int wv = tid >> 6;
    int lane = tid & 63;
    int half = lane >> 5;
    int c0 = (lane & 31) * 4;   // column (floats); 32 lanes x float4 = full row

    #pragma unroll
    for (int rr = 0; rr < 2; ++rr) {
        int row = row0 + wv * 4 + half * 2 + rr;
        float di = dinv[row];
        float4 a = *(const float4*)&xin[row * DIM + c0];
        a.x *= di; a.y *= di; a.z *= di; a.w *= di;   // self term: di*(di*x) after final scale
        int p = rowptr[row], p1 = rowptr[row + 1];
        for (; p + 8 <= p1; p += 8) {
            int2 e0 = epack[p + 0], e1 = epack[p + 1], e2 = epack[p + 2], e3 = epack[p + 3];
            int2 e4 = epack[p + 4], e5 = epack[p + 5], e6 = epack[p + 6], e7 = epack[p + 7];
            float4 v0 = *(const float4*)&xin[e0.x * DIM + c0];
            float4 v1 = *(const float4*)&xin[e1.x * DIM + c0];
            float4 v2 = *(const float4*)&xin[e2.x * DIM + c0];
            float4 v3 = *(const float4*)&xin[e3.x * DIM + c0];
            float4 v4 = *(const float4*)&xin[e4.x * DIM + c0];
            float4 v5 = *(const float4*)&xin[e5.x * DIM + c0];
            float4 v6 = *(const float4*)&xin[e6.x * DIM + c0];
            float4 v7 = *(const float4*)&xin[e7.x * DIM + c0];
            float c;
            c = __int_as_float(e0.y);
            a.x = fmaf(c, v0.x, a.x); a.y = fmaf(c, v0.y, a.y);
            a.z = fmaf(c, v0.z, a.z); a.w = fmaf(c, v0.w, a.w);
            c = __int_as_float(e1.y);
            a.x = fmaf(c, v1.x, a.x); a.y = fmaf(c, v1.y, a.y);
            a.z = fmaf(c, v1.z, a.z); a.w = fmaf(c, v1.w, a.w);
            c = __int_as_float(e2.y);
            a.x = fmaf(c, v2.x, a.x); a.y = fmaf(c, v2.y, a.y);
            a.z = fmaf(c, v2.z, a.z); a.w = fmaf(c, v2.w, a.w);
            c = __int_as_float(e3.y);
            a.x = fmaf(c, v3.x, a.x); a.y = fmaf(c, v3.y, a.y);
            a.z = fmaf(c, v3.z, a.z); a.w = fmaf(c, v3.w, a.w);
            c = __int_as_float(e4.y);
            a.x = fmaf(c, v4.x, a.x); a.y = fmaf(c, v4.y, a.y);
            a.z = fmaf(c, v4.z, a.z); a.w = fmaf(c, v4.w, a.w);
            c = __int_as_float(e5.y);
            a.x = fmaf(c, v5.x, a.x); a.y = fmaf(c, v5.y, a.y);
            a.z = fmaf(c, v5.z, a.z); a.w = fmaf(c, v5.w, a.w);
            c = __int_as_float(e6.y);
            a.x = fmaf(c, v6.x, a.x); a.y = fmaf(c, v6.y, a.y);
            a.z = fmaf(c, v6.z, a.z); a.w = fmaf(c, v6.w, a.w);
            c = __int_as_float(e7.y);
            a.x = fmaf(c, v7.x, a.x); a.y = fmaf(c, v7.y, a.y);
            a.z = fmaf(c, v7.z, a.z); a.w = fmaf(c, v7.w, a.w);
        }
        for (; p < p1; ++p) {
            int2 e = epack[p];
            float4 v = *(const float4*)&xin[e.x * DIM + c0];
            float c = __int_as_float(e.y);
            a.x = fmaf(c, v.x, a.x); a.y = fmaf(c, v.y, a.y);
            a.z = fmaf(c, v.z, a.z); a.w = fmaf(c, v.w, a.w);
        }
        a.x *= di; a.y *= di; a.z *= di; a.w *= di;   // fold dinv[dst]
        *(float4*)&Xs[wv * 4 + half * 2 + rr][c0] = a;
    }
    __syncthreads();

    // GEMM 16x128
    int tx = tid & 31, ty = tid >> 5;
    float acc[2][4] = {};
    for (int k = 0; k < DIM; k += 4) {
        float4 xv[2];
        #pragma unroll
        for (int r = 0; r < 2; ++r) xv[r] = *(const float4*)&Xs[ty * 2 + r][k];
        #pragma unroll
        for (int kk = 0; kk < 4; ++kk) {
            float4 wv2 = *(const float4*)&W[(k + kk) * DIM + tx * 4];
            #pragma unroll
            for (int r = 0; r < 2; ++r) {
                float xs = (&xv[r].x)[kk];
                acc[r][0] = fmaf(xs, wv2.x, acc[r][0]);
                acc[r][1] = fmaf(xs, wv2.y, acc[r][1]);
                acc[r][2] = fmaf(xs, wv2.z, acc[r][2]);
                acc[r][3] = fmaf(xs, wv2.w, acc[r][3]);
            }
        }
    }

    float4 bv = *(const float4*)&b[tx * 4];
    #pragma unroll
    for (int r = 0; r < 2; ++r) {
        int row = row0 + ty * 2 + r;
        float4 v;
        v.x = acc[r][0] + bv.x; v.y = acc[r][1] + bv.y;
        v.z = acc[r][2] + bv.z; v.w = acc[r][3] + bv.w;
        if (LEAKY) {
            v.x = v.x > 0.f ? v.x : NEG_SLOPE * v.x;
            v.y = v.y > 0.f ? v.y : NEG_SLOPE * v.y;
            v.z = v.z > 0.f ? v.z : NEG_SLOPE * v.z;
            v.w = v.w > 0.f ? v.w : NEG_SLOPE * v.w;
        }
        *(float4*)&out[row * DIM + tx * 4] = v;
    }
}

extern "C" void kernel_launch(void* const* d_in, const int* in_sizes, int n_in,
                              void* d_out, int out_size, void* d_ws, size_t ws_size,
                              hipStream_t stream) {
    const float* x     = (const float*)d_in[0];
    const int*   ei    = (const int*)d_in[1];
    const float* attr  = (const float*)d_in[2];
    const int*   etype = (const int*)d_in[3];
    const float* scale = (const float*)d_in[4];
    const float* W1 = (const float*)d_in[5];
    const float* b1 = (const float*)d_in[6];
    const float* W2 = (const float*)d_in[7];
    const float* b2 = (const float*)d_in[8];
    const float* W3 = (const float*)d_in[9];
    const float* b3 = (const float*)d_in[10];
    float* out = (float*)d_out;

    // ws layout:
    float* B2     = (float*)d_ws;              // NN*DIM
    int2*  epack  = (int2*)(B2 + NN * DIM);    // NE int2 (packed src+coef)
    float* dinv   = (float*)(epack + NE);      // NN (deg -> dinv in place)
    int*   hist   = (int*)(dinv + NN);         // NN (hist -> cursor)
    int*   rowptr = hist + NN;                 // NN+1
    int*   aux    = rowptr + NN + 1;           // 64

    const int nb_n = (NN + 255) / 256;         // 196
    const int nb_e = NE / 256;                 // 3125
    const int nb_l = NN / 16;                  // 3125 (exact)
    const int nb_s1 = (NN + 1023) / 1024;      // 49

    k_init<<<nb_n, 256, 0, stream>>>(dinv, hist);
    k_deg_hist<<<nb_e, 256, 0, stream>>>(ei, attr, etype, scale, dinv, hist);
    k_scan1<<<nb_s1, 256, 0, stream>>>(hist, rowptr, aux, dinv);
    k_scan2<<<1, 64, 0, stream>>>(aux);
    k_scan3<<<nb_n, 256, 0, stream>>>(rowptr, hist, aux);
    k_place<<<nb_e, 256, 0, stream>>>(ei, attr, etype, scale, dinv, hist, epack);

    // layer 1: x -> d_out ; layer 2: d_out -> B2 ; layer 3: B2 -> d_out
    k_layer<true ><<<nb_l, 256, 0, stream>>>(x,   epack, rowptr, dinv, W1, b1, out);
    k_layer<true ><<<nb_l, 256, 0, stream>>>(out, epack, rowptr, dinv, W2, b2, B2);
    k_layer<false><<<nb_l, 256, 0, stream>>>(B2,  epack, rowptr, dinv, W3, b3, out);
}

// Round 5
// 400.298 us; speedup vs baseline: 1.0981x; 1.0981x over previous
//
#include <hip/hip_runtime.h>

#define NN 50000
#define NE 800000
#define NEPAD (NE + NN + 16)   // even-padded CSR capacity
#define DIM 128
#define NEG_SLOPE 0.1f

// ---------- preprocessing: CSR-by-dst build (counts padded to even) ----------

__global__ void k_init(float* __restrict__ deg, int* __restrict__ hist) {
    int i = blockIdx.x * 256 + threadIdx.x;
    if (i < NN) { deg[i] = 1.0f; hist[i] = 0; }   // self-loop weight 1
}

__global__ void k_deg_hist(const int* __restrict__ ei, const float* __restrict__ attr,
                           const int* __restrict__ etype, const float* __restrict__ scale,
                           float* __restrict__ deg, int* __restrict__ hist) {
    int e = blockIdx.x * 256 + threadIdx.x;
    if (e >= NE) return;
    float w = scale[etype[e]] * attr[e];
    int d = ei[NE + e];
    atomicAdd(&deg[d], w);
    atomicAdd(&hist[d], 1);
}

// scan1: per-block (1024 elems) exclusive scan of EVEN-PADDED counts -> rowptr,
// block sums -> aux. Also converts deg -> dinv in place.
__global__ void k_scan1(const int* __restrict__ hist, int* __restrict__ rowptr,
                        int* __restrict__ aux, float* __restrict__ deg) {
    __shared__ int sdata[256];
    int t = threadIdx.x;
    int base = blockIdx.x * 1024 + t * 4;
    int v[4]; int s = 0;
    #pragma unroll
    for (int j = 0; j < 4; ++j) {
        v[j] = (base + j < NN) ? ((hist[base + j] + 1) & ~1) : 0;  // pad to even
        s += v[j];
    }
    #pragma unroll
    for (int j = 0; j < 4; ++j) {
        if (base + j < NN) {
            float d = deg[base + j];
            deg[base + j] = d > 0.0f ? (1.0f / sqrtf(d)) : 0.0f;
        }
    }
    sdata[t] = s;
    __syncthreads();
    for (int off = 1; off < 256; off <<= 1) {
        int x = (t >= off) ? sdata[t - off] : 0;
        __syncthreads();
        sdata[t] += x;
        __syncthreads();
    }
    int run = sdata[t] - s;
    if (t == 255) aux[blockIdx.x] = sdata[255];
    #pragma unroll
    for (int j = 0; j < 4; ++j) { if (base + j < NN) rowptr[base + j] = run; run += v[j]; }
}

// scan3 (fused): every block redundantly scans the 49 block sums in wave 0,
// then adds its offset; init cursor = rowptr; thread 0 of block 0 writes rowptr[NN].
__global__ void k_scan3(int* __restrict__ rowptr, int* __restrict__ cursor,
                        const int* __restrict__ aux) {
    __shared__ int exs[64];
    __shared__ int stot;
    int t = threadIdx.x;
    if (t < 64) {
        int v = (t < 49) ? aux[t] : 0;
        int orig = v;
        for (int off = 1; off < 64; off <<= 1) {
            int y = __shfl_up(v, off, 64);
            if (t >= off) v += y;
        }
        exs[t] = v - orig;
        if (t == 48) stot = v;   // inclusive total
    }
    __syncthreads();
    int i = blockIdx.x * 256 + t;
    if (i < NN) {
        int v = rowptr[i] + exs[i >> 10];
        rowptr[i] = v;
        cursor[i] = v;
    }
    if (i == 0) rowptr[NN] = stot;
}

// place edges into CSR order; store packed {src, dinv[src]*w}. Gaps up to the
// padded row end stay {0, 0.0f} (pre-zeroed) -> contribute exactly 0.
__global__ void k_place(const int* __restrict__ ei, const float* __restrict__ attr,
                        const int* __restrict__ etype, const float* __restrict__ scale,
                        const float* __restrict__ dinv, int* __restrict__ cursor,
                        int2* __restrict__ epack) {
    int e = blockIdx.x * 256 + threadIdx.x;
    if (e >= NE) return;
    int s = ei[e], d = ei[NE + e];
    float w = scale[etype[e]] * attr[e];
    int pos = atomicAdd(&cursor[d], 1);
    int2 pk; pk.x = s; pk.y = __float_as_int(dinv[s] * w);
    epack[pos] = pk;
}

// ---------- fused layer ----------
// Block = 256 threads = 4 waves = 8 streams; 32 dst rows/block (grid 1563, guards).
// Stream = 32 lanes, float4/lane (full 512B row per gather). Each stream walks 4
// rows serially; per row the edge loop keeps 8 gathers + next meta int4s in
// flight, pinned by sched_barrier(0). GEMM: 32x128 register-blocked from LDS.

#define GF8(EA0, EA1, EA2, EA3) do {                                         \
    float4 g0 = xin4[EA0.x * 32 + cl];                                       \
    float4 g1 = xin4[EA0.z * 32 + cl];                                       \
    float4 g2 = xin4[EA1.x * 32 + cl];                                       \
    float4 g3 = xin4[EA1.z * 32 + cl];                                       \
    float4 g4 = xin4[EA2.x * 32 + cl];                                       \
    float4 g5 = xin4[EA2.z * 32 + cl];                                       \
    float4 g6 = xin4[EA3.x * 32 + cl];                                       \
    float4 g7 = xin4[EA3.z * 32 + cl];                                       \
    __builtin_amdgcn_sched_barrier(0);                                       \
    float cc;                                                                \
    cc = __int_as_float(EA0.y);                                              \
    a.x = fmaf(cc, g0.x, a.x); a.y = fmaf(cc, g0.y, a.y);                    \
    a.z = fmaf(cc, g0.z, a.z); a.w = fmaf(cc, g0.w, a.w);                    \
    cc = __int_as_float(EA0.w);                                              \
    a.x = fmaf(cc, g1.x, a.x); a.y = fmaf(cc, g1.y, a.y);                    \
    a.z = fmaf(cc, g1.z, a.z); a.w = fmaf(cc, g1.w, a.w);                    \
    cc = __int_as_float(EA1.y);                                              \
    a.x = fmaf(cc, g2.x, a.x); a.y = fmaf(cc, g2.y, a.y);                    \
    a.z = fmaf(cc, g2.z, a.z); a.w = fmaf(cc, g2.w, a.w);                    \
    cc = __int_as_float(EA1.w);                                              \
    a.x = fmaf(cc, g3.x, a.x); a.y = fmaf(cc, g3.y, a.y);                    \
    a.z = fmaf(cc, g3.z, a.z); a.w = fmaf(cc, g3.w, a.w);                    \
    cc = __int_as_float(EA2.y);                                              \
    a.x = fmaf(cc, g4.x, a.x); a.y = fmaf(cc, g4.y, a.y);                    \
    a.z = fmaf(cc, g4.z, a.z); a.w = fmaf(cc, g4.w, a.w);                    \
    cc = __int_as_float(EA2.w);                                              \
    a.x = fmaf(cc, g5.x, a.x); a.y = fmaf(cc, g5.y, a.y);                    \
    a.z = fmaf(cc, g5.z, a.z); a.w = fmaf(cc, g5.w, a.w);                    \
    cc = __int_as_float(EA3.y);                                              \
    a.x = fmaf(cc, g6.x, a.x); a.y = fmaf(cc, g6.y, a.y);                    \
    a.z = fmaf(cc, g6.z, a.z); a.w = fmaf(cc, g6.w, a.w);                    \
    cc = __int_as_float(EA3.w);                                              \
    a.x = fmaf(cc, g7.x, a.x); a.y = fmaf(cc, g7.y, a.y);                    \
    a.z = fmaf(cc, g7.z, a.z); a.w = fmaf(cc, g7.w, a.w);                    \
} while (0)

template<bool LEAKY>
__global__ __launch_bounds__(256, 4)
void k_layer(const float* __restrict__ xin, const int2* __restrict__ epack,
             const int* __restrict__ rowptr, const float* __restrict__ dinv,
             const float* __restrict__ W, const float* __restrict__ b,
             float* __restrict__ out) {
    __shared__ float Xs[32][132];
    const float4* __restrict__ xin4 = (const float4*)xin;
    int tid = threadIdx.x;
    int row0 = blockIdx.x * 32;
    int st = tid >> 5;          // stream 0..7
    int cl = tid & 31;          // float4 column within row

    #pragma unroll
    for (int rr = 0; rr < 4; ++rr) {
        int row = row0 + st * 4 + rr;
        if (row < NN) {
            float di = dinv[row];
            float4 a = xin4[row * 32 + cl];
            a.x *= di; a.y *= di; a.z *= di; a.w *= di;
            int p = rowptr[row], p1 = rowptr[row + 1];
            if (p + 8 <= p1) {
                const int4* q = (const int4*)&epack[p];
                int4 ea0 = q[0], ea1 = q[1], ea2 = q[2], ea3 = q[3];
                p += 8;
                while (p + 8 <= p1) {
                    const int4* q2 = (const int4*)&epack[p];
                    int4 eb0 = q2[0], eb1 = q2[1], eb2 = q2[2], eb3 = q2[3];
                    GF8(ea0, ea1, ea2, ea3);
                    ea0 = eb0; ea1 = eb1; ea2 = eb2; ea3 = eb3;
                    p += 8;
                }
                GF8(ea0, ea1, ea2, ea3);
            }
            for (; p < p1; p += 2) {       // p stays even (padded counts)
                int4 e = *(const int4*)&epack[p];
                float4 u0 = xin4[e.x * 32 + cl];
                float4 u1 = xin4[e.z * 32 + cl];
                float cc = __int_as_float(e.y);
                a.x = fmaf(cc, u0.x, a.x); a.y = fmaf(cc, u0.y, a.y);
                a.z = fmaf(cc, u0.z, a.z); a.w = fmaf(cc, u0.w, a.w);
                cc = __int_as_float(e.w);
                a.x = fmaf(cc, u1.x, a.x); a.y = fmaf(cc, u1.y, a.y);
                a.z = fmaf(cc, u1.z, a.z); a.w = fmaf(cc, u1.w, a.w);
            }
            a.x *= di; a.y *= di; a.z *= di; a.w *= di;   // fold dinv[dst]
            *(float4*)&Xs[st * 4 + rr][cl * 4] = a;
        }
    }
    __syncthreads();

    // GEMM 32x128
    int tx = tid & 31, ty = tid >> 5;
    float acc[4][4] = {};
    for (int k = 0; k < DIM; k += 4) {
        float4 xv[4];
        #pragma unroll
        for (int r = 0; r < 4; ++r) xv[r] = *(const float4*)&Xs[ty * 4 + r][k];
        #pragma unroll
        for (int kk = 0; kk < 4; ++kk) {
            float4 wv2 = *(const float4*)&W[(k + kk) * DIM + tx * 4];
            #pragma unroll
            for (int r = 0; r < 4; ++r) {
                float xs = (&xv[r].x)[kk];
                acc[r][0] = fmaf(xs, wv2.x, acc[r][0]);
                acc[r][1] = fmaf(xs, wv2.y, acc[r][1]);
                acc[r][2] = fmaf(xs, wv2.z, acc[r][2]);
                acc[r][3] = fmaf(xs, wv2.w, acc[r][3]);
            }
        }
    }

    float4 bv = *(const float4*)&b[tx * 4];
    #pragma unroll
    for (int r = 0; r < 4; ++r) {
        int row = row0 + ty * 4 + r;
        if (row >= NN) continue;
        float4 v;
        v.x = acc[r][0] + bv.x; v.y = acc[r][1] + bv.y;
        v.z = acc[r][2] + bv.z; v.w = acc[r][3] + bv.w;
        if (LEAKY) {
            v.x = v.x > 0.f ? v.x : NEG_SLOPE * v.x;
            v.y = v.y > 0.f ? v.y : NEG_SLOPE * v.y;
            v.z = v.z > 0.f ? v.z : NEG_SLOPE * v.z;
            v.w = v.w > 0.f ? v.w : NEG_SLOPE * v.w;
        }
        *(float4*)&out[row * DIM + tx * 4] = v;
    }
}

extern "C" void kernel_launch(void* const* d_in, const int* in_sizes, int n_in,
                              void* d_out, int out_size, void* d_ws, size_t ws_size,
                              hipStream_t stream) {
    const float* x     = (const float*)d_in[0];
    const int*   ei    = (const int*)d_in[1];
    const float* attr  = (const float*)d_in[2];
    const int*   etype = (const int*)d_in[3];
    const float* scale = (const float*)d_in[4];
    const float* W1 = (const float*)d_in[5];
    const float* b1 = (const float*)d_in[6];
    const float* W2 = (const float*)d_in[7];
    const float* b2 = (const float*)d_in[8];
    const float* W3 = (const float*)d_in[9];
    const float* b3 = (const float*)d_in[10];
    float* out = (float*)d_out;

    // ws layout:
    float* B2     = (float*)d_ws;               // NN*DIM
    int2*  epack  = (int2*)(B2 + NN * DIM);     // NEPAD packed edges
    float* dinv   = (float*)(epack + NEPAD);    // NN
    int*   hist   = (int*)(dinv + NN);          // NN (counts -> cursor)
    int*   rowptr = hist + NN;                  // NN+1
    int*   aux    = rowptr + NN + 1;            // 64

    const int nb_n = (NN + 255) / 256;          // 196
    const int nb_e = NE / 256;                  // 3125
    const int nb_l = (NN + 31) / 32;            // 1563
    const int nb_s1 = (NN + 1023) / 1024;       // 49

    hipMemsetAsync(epack, 0, (size_t)NEPAD * sizeof(int2), stream);  // dummy edges
    k_init<<<nb_n, 256, 0, stream>>>(dinv, hist);
    k_deg_hist<<<nb_e, 256, 0, stream>>>(ei, attr, etype, scale, dinv, hist);
    k_scan1<<<nb_s1, 256, 0, stream>>>(hist, rowptr, aux, dinv);
    k_scan3<<<nb_n, 256, 0, stream>>>(rowptr, hist, aux);
    k_place<<<nb_e, 256, 0, stream>>>(ei, attr, etype, scale, dinv, hist, epack);

    // layer 1: x -> d_out ; layer 2: d_out -> B2 ; layer 3: B2 -> d_out
    k_layer<true ><<<nb_l, 256, 0, stream>>>(x,   epack, rowptr, dinv, W1, b1, out);
    k_layer<true ><<<nb_l, 256, 0, stream>>>(out, epack, rowptr, dinv, W2, b2, B2);
    k_layer<false><<<nb_l, 256, 0, stream>>>(B2,  epack, rowptr, dinv, W3, b3, out);
}

// Round 6
// 328.648 us; speedup vs baseline: 1.3375x; 1.2180x over previous
//
#include <hip/hip_runtime.h>
#include <hip/hip_fp16.h>

#define NN 50000
#define NE 800000
#define NEPAD (NE + NN + 16)   // even-padded CSR capacity
#define DIM 128
#define NEG_SLOPE 0.1f

// ---------- preprocessing: CSR-by-dst build (counts padded to even) ----------

__global__ void k_init(float* __restrict__ deg, int* __restrict__ hist) {
    int i = blockIdx.x * 256 + threadIdx.x;
    if (i < NN) { deg[i] = 1.0f; hist[i] = 0; }   // self-loop weight 1
}

__global__ void k_deg_hist(const int* __restrict__ ei, const float* __restrict__ attr,
                           const int* __restrict__ etype, const float* __restrict__ scale,
                           float* __restrict__ deg, int* __restrict__ hist) {
    int e = blockIdx.x * 256 + threadIdx.x;
    if (e >= NE) return;
    float w = scale[etype[e]] * attr[e];
    int d = ei[NE + e];
    atomicAdd(&deg[d], w);
    atomicAdd(&hist[d], 1);
}

// scan1: per-block (1024 elems) exclusive scan of EVEN-PADDED counts -> rowptr,
// block sums -> aux. Also converts deg -> dinv in place.
__global__ void k_scan1(const int* __restrict__ hist, int* __restrict__ rowptr,
                        int* __restrict__ aux, float* __restrict__ deg) {
    __shared__ int sdata[256];
    int t = threadIdx.x;
    int base = blockIdx.x * 1024 + t * 4;
    int v[4]; int s = 0;
    #pragma unroll
    for (int j = 0; j < 4; ++j) {
        v[j] = (base + j < NN) ? ((hist[base + j] + 1) & ~1) : 0;  // pad to even
        s += v[j];
    }
    #pragma unroll
    for (int j = 0; j < 4; ++j) {
        if (base + j < NN) {
            float d = deg[base + j];
            deg[base + j] = d > 0.0f ? (1.0f / sqrtf(d)) : 0.0f;
        }
    }
    sdata[t] = s;
    __syncthreads();
    for (int off = 1; off < 256; off <<= 1) {
        int x = (t >= off) ? sdata[t - off] : 0;
        __syncthreads();
        sdata[t] += x;
        __syncthreads();
    }
    int run = sdata[t] - s;
    if (t == 255) aux[blockIdx.x] = sdata[255];
    #pragma unroll
    for (int j = 0; j < 4; ++j) { if (base + j < NN) rowptr[base + j] = run; run += v[j]; }
}

// scan3 (fused): every block redundantly scans the 49 block sums in wave 0,
// then adds its offset; init cursor = rowptr.
__global__ void k_scan3(int* __restrict__ rowptr, int* __restrict__ cursor,
                        const int* __restrict__ aux) {
    __shared__ int exs[64];
    __shared__ int stot;
    int t = threadIdx.x;
    if (t < 64) {
        int v = (t < 49) ? aux[t] : 0;
        int orig = v;
        for (int off = 1; off < 64; off <<= 1) {
            int y = __shfl_up(v, off, 64);
            if (t >= off) v += y;
        }
        exs[t] = v - orig;
        if (t == 48) stot = v;
    }
    __syncthreads();
    int i = blockIdx.x * 256 + t;
    if (i < NN) {
        int v = rowptr[i] + exs[i >> 10];
        rowptr[i] = v;
        cursor[i] = v;
    }
    if (i == 0) rowptr[NN] = stot;
}

// place edges into CSR order; store packed {src, dinv[src]*w}. Padding gaps stay
// {0, 0.0f} (pre-zeroed) -> contribute exactly 0.
__global__ void k_place(const int* __restrict__ ei, const float* __restrict__ attr,
                        const int* __restrict__ etype, const float* __restrict__ scale,
                        const float* __restrict__ dinv, int* __restrict__ cursor,
                        int2* __restrict__ epack) {
    int e = blockIdx.x * 256 + threadIdx.x;
    if (e >= NE) return;
    int s = ei[e], d = ei[NE + e];
    float w = scale[etype[e]] * attr[e];
    int pos = atomicAdd(&cursor[d], 1);
    int2 pk; pk.x = s; pk.y = __float_as_int(dinv[s] * w);
    epack[pos] = pk;
}

// fp32 -> fp16 shadow copy of the feature matrix (16B in -> 8B out per thread)
__global__ void k_half(const float4* __restrict__ x4, uint2* __restrict__ xh) {
    int i = blockIdx.x * 256 + threadIdx.x;     // float4 index, NN*DIM/4 total
    if (i >= NN * DIM / 4) return;
    float4 v = x4[i];
    __half2 h0 = __float22half2_rn(make_float2(v.x, v.y));
    __half2 h1 = __float22half2_rn(make_float2(v.z, v.w));
    uint2 pk;
    pk.x = *(const unsigned int*)&h0;
    pk.y = *(const unsigned int*)&h1;
    xh[i] = pk;
}

// ---------- fused layer (fp16 gather, fp32 accumulate/GEMM) ----------
// Block = 256 threads = 8 streams of 32 lanes; 32 dst rows/block.
// A stream covers a full 256B fp16 row (8B/lane); depth-8 gather pipeline
// pinned by sched_barrier(0). GEMM: 32x128 register-blocked fp32 from LDS.

#define CVT_FMA(GU, CBITS) do {                                              \
    const __half2* hp_ = (const __half2*)&(GU);                              \
    float2 f0_ = __half22float2(hp_[0]);                                     \
    float2 f1_ = __half22float2(hp_[1]);                                     \
    float cc_ = __int_as_float(CBITS);                                       \
    a.x = fmaf(cc_, f0_.x, a.x); a.y = fmaf(cc_, f0_.y, a.y);                \
    a.z = fmaf(cc_, f1_.x, a.z); a.w = fmaf(cc_, f1_.y, a.w);                \
} while (0)

#define GF8H(EA0, EA1, EA2, EA3) do {                                        \
    uint2 g0 = xh[EA0.x * 32 + cl];                                          \
    uint2 g1 = xh[EA0.z * 32 + cl];                                          \
    uint2 g2 = xh[EA1.x * 32 + cl];                                          \
    uint2 g3 = xh[EA1.z * 32 + cl];                                          \
    uint2 g4 = xh[EA2.x * 32 + cl];                                          \
    uint2 g5 = xh[EA2.z * 32 + cl];                                          \
    uint2 g6 = xh[EA3.x * 32 + cl];                                          \
    uint2 g7 = xh[EA3.z * 32 + cl];                                          \
    __builtin_amdgcn_sched_barrier(0);                                       \
    CVT_FMA(g0, EA0.y); CVT_FMA(g1, EA0.w);                                  \
    CVT_FMA(g2, EA1.y); CVT_FMA(g3, EA1.w);                                  \
    CVT_FMA(g4, EA2.y); CVT_FMA(g5, EA2.w);                                  \
    CVT_FMA(g6, EA3.y); CVT_FMA(g7, EA3.w);                                  \
} while (0)

template<bool LEAKY, bool WRITE_HALF>
__global__ __launch_bounds__(256, 4)
void k_layer(const uint2* __restrict__ xh, const int2* __restrict__ epack,
             const int* __restrict__ rowptr, const float* __restrict__ dinv,
             const float* __restrict__ W, const float* __restrict__ b,
             uint2* __restrict__ outh, float* __restrict__ outf) {
    __shared__ float Xs[32][132];
    int tid = threadIdx.x;
    int row0 = blockIdx.x * 32;
    int st = tid >> 5;          // stream 0..7
    int cl = tid & 31;          // 8B column chunk within row (4 halves)

    #pragma unroll
    for (int rr = 0; rr < 4; ++rr) {
        int row = row0 + st * 4 + rr;
        if (row < NN) {
            float di = dinv[row];
            // self term from fp16 shadow (rel err 2.4e-4 on a small term)
            uint2 sg = xh[row * 32 + cl];
            const __half2* sp = (const __half2*)&sg;
            float2 s0 = __half22float2(sp[0]);
            float2 s1 = __half22float2(sp[1]);
            float4 a;
            a.x = di * s0.x; a.y = di * s0.y; a.z = di * s1.x; a.w = di * s1.y;
            int p = rowptr[row], p1 = rowptr[row + 1];
            if (p + 8 <= p1) {
                const int4* q = (const int4*)&epack[p];
                int4 ea0 = q[0], ea1 = q[1], ea2 = q[2], ea3 = q[3];
                p += 8;
                while (p + 8 <= p1) {
                    const int4* q2 = (const int4*)&epack[p];
                    int4 eb0 = q2[0], eb1 = q2[1], eb2 = q2[2], eb3 = q2[3];
                    GF8H(ea0, ea1, ea2, ea3);
                    ea0 = eb0; ea1 = eb1; ea2 = eb2; ea3 = eb3;
                    p += 8;
                }
                GF8H(ea0, ea1, ea2, ea3);
            }
            for (; p < p1; p += 2) {       // p stays even (padded counts)
                int4 e = *(const int4*)&epack[p];
                uint2 u0 = xh[e.x * 32 + cl];
                uint2 u1 = xh[e.z * 32 + cl];
                CVT_FMA(u0, e.y);
                CVT_FMA(u1, e.w);
            }
            a.x *= di; a.y *= di; a.z *= di; a.w *= di;   // fold dinv[dst]
            *(float4*)&Xs[st * 4 + rr][cl * 4] = a;
        }
    }
    __syncthreads();

    // GEMM 32x128 (fp32)
    int tx = tid & 31, ty = tid >> 5;
    float acc[4][4] = {};
    for (int k = 0; k < DIM; k += 4) {
        float4 xv[4];
        #pragma unroll
        for (int r = 0; r < 4; ++r) xv[r] = *(const float4*)&Xs[ty * 4 + r][k];
        #pragma unroll
        for (int kk = 0; kk < 4; ++kk) {
            float4 wv2 = *(const float4*)&W[(k + kk) * DIM + tx * 4];
            #pragma unroll
            for (int r = 0; r < 4; ++r) {
                float xs = (&xv[r].x)[kk];
                acc[r][0] = fmaf(xs, wv2.x, acc[r][0]);
                acc[r][1] = fmaf(xs, wv2.y, acc[r][1]);
                acc[r][2] = fmaf(xs, wv2.z, acc[r][2]);
                acc[r][3] = fmaf(xs, wv2.w, acc[r][3]);
            }
        }
    }

    float4 bv = *(const float4*)&b[tx * 4];
    #pragma unroll
    for (int r = 0; r < 4; ++r) {
        int row = row0 + ty * 4 + r;
        if (row >= NN) continue;
        float4 v;
        v.x = acc[r][0] + bv.x; v.y = acc[r][1] + bv.y;
        v.z = acc[r][2] + bv.z; v.w = acc[r][3] + bv.w;
        if (LEAKY) {
            v.x = v.x > 0.f ? v.x : NEG_SLOPE * v.x;
            v.y = v.y > 0.f ? v.y : NEG_SLOPE * v.y;
            v.z = v.z > 0.f ? v.z : NEG_SLOPE * v.z;
            v.w = v.w > 0.f ? v.w : NEG_SLOPE * v.w;
        }
        if (WRITE_HALF) {
            __half2 h0 = __float22half2_rn(make_float2(v.x, v.y));
            __half2 h1 = __float22half2_rn(make_float2(v.z, v.w));
            uint2 pk;
            pk.x = *(const unsigned int*)&h0;
            pk.y = *(const unsigned int*)&h1;
            outh[row * 32 + tx] = pk;
        } else {
            *(float4*)&outf[row * DIM + tx * 4] = v;
        }
    }
}

extern "C" void kernel_launch(void* const* d_in, const int* in_sizes, int n_in,
                              void* d_out, int out_size, void* d_ws, size_t ws_size,
                              hipStream_t stream) {
    const float* x     = (const float*)d_in[0];
    const int*   ei    = (const int*)d_in[1];
    const float* attr  = (const float*)d_in[2];
    const int*   etype = (const int*)d_in[3];
    const float* scale = (const float*)d_in[4];
    const float* W1 = (const float*)d_in[5];
    const float* b1 = (const float*)d_in[6];
    const float* W2 = (const float*)d_in[7];
    const float* b2 = (const float*)d_in[8];
    const float* W3 = (const float*)d_in[9];
    const float* b3 = (const float*)d_in[10];
    float* out = (float*)d_out;

    // ws layout:
    uint2* xhA    = (uint2*)d_ws;               // NN*32 uint2 (12.8 MB)
    uint2* xhB    = xhA + NN * 32;              // NN*32 uint2 (12.8 MB)
    int2*  epack  = (int2*)(xhB + NN * 32);     // NEPAD packed edges (6.8 MB)
    float* dinv   = (float*)(epack + NEPAD);    // NN
    int*   hist   = (int*)(dinv + NN);          // NN (counts -> cursor)
    int*   rowptr = hist + NN;                  // NN+1
    int*   aux    = rowptr + NN + 1;            // 64

    const int nb_n = (NN + 255) / 256;          // 196
    const int nb_e = NE / 256;                  // 3125
    const int nb_l = (NN + 31) / 32;            // 1563
    const int nb_s1 = (NN + 1023) / 1024;       // 49
    const int nb_h = (NN * DIM / 4 + 255) / 256;

    hipMemsetAsync(epack, 0, (size_t)NEPAD * sizeof(int2), stream);  // dummy edges
    k_init<<<nb_n, 256, 0, stream>>>(dinv, hist);
    k_deg_hist<<<nb_e, 256, 0, stream>>>(ei, attr, etype, scale, dinv, hist);
    k_scan1<<<nb_s1, 256, 0, stream>>>(hist, rowptr, aux, dinv);
    k_scan3<<<nb_n, 256, 0, stream>>>(rowptr, hist, aux);
    k_place<<<nb_e, 256, 0, stream>>>(ei, attr, etype, scale, dinv, hist, epack);
    k_half<<<nb_h, 256, 0, stream>>>((const float4*)x, xhA);

    // layer 1: xhA -> xhB (fp16) ; layer 2: xhB -> xhA (fp16) ; layer 3: xhA -> d_out (fp32)
    k_layer<true,  true ><<<nb_l, 256, 0, stream>>>(xhA, epack, rowptr, dinv, W1, b1, xhB, nullptr);
    k_layer<true,  true ><<<nb_l, 256, 0, stream>>>(xhB, epack, rowptr, dinv, W2, b2, xhA, nullptr);
    k_layer<false, false><<<nb_l, 256, 0, stream>>>(xhA, epack, rowptr, dinv, W3, b3, nullptr, out);
}